// Round 3
// 3337.263 us; speedup vs baseline: 1.1513x; 1.1513x over previous
//
#include <hip/hip_runtime.h>
#include <hip/hip_bf16.h>

// Problem constants
#define B_ 128
#define T_ 1024
#define D_ 512
#define H_ 256
#define G_ 1024   // 4*H

typedef __bf16 bf16_t;
typedef __bf16 bf16x8 __attribute__((ext_vector_type(8)));
typedef __bf16 bf16x4 __attribute__((ext_vector_type(4)));
typedef float  f32x4  __attribute__((ext_vector_type(4)));

__device__ __forceinline__ float fast_rcp(float x) { return __builtin_amdgcn_rcpf(x); }

__device__ __forceinline__ float sigmoid_f(float x) {
  return fast_rcp(1.0f + __expf(-x));
}
__device__ __forceinline__ float tanh_f(float x) {
  x = fminf(fmaxf(x, -15.0f), 15.0f);   // avoid inf/inf NaN
  float e = __expf(-2.0f * x);
  return (1.0f - e) * fast_rcp(1.0f + e);
}

// Workgroup barrier that waits only on LDS ops (lgkmcnt). Unlike
// __syncthreads(), this does NOT drain vmcnt — our in-flight global loads are
// lane-private prefetches that no other thread depends on. h propagates
// through LDS, which lgkmcnt(0) covers. "memory" clobber = compiler fence.
__device__ __forceinline__ void barrier_lds_only() {
  asm volatile("s_waitcnt lgkmcnt(0)\n\ts_barrier" ::: "memory");
}

// ---------------------------------------------------------------------------
// prep: W_hh fp32 -> bf16, bias = b_ih + b_hh   (identical to round-0)
// ---------------------------------------------------------------------------
__global__ __launch_bounds__(256) void prep_kernel(
    const float* __restrict__ Whh, const float* __restrict__ bih,
    const float* __restrict__ bhh, bf16_t* __restrict__ whhb,
    float* __restrict__ bias) {
  int i = blockIdx.x * 256 + threadIdx.x;
  if (i < G_ * H_) whhb[i] = (bf16_t)Whh[i];
  if (i < G_) bias[i] = bih[i] + bhh[i];
}

// ---------------------------------------------------------------------------
// xg2[row][c][gamma] = (X @ W_ih^T + b)[row][gamma*256+c], bf16, row = b*T+t.
// v3: M-tile 128 with 8 waves (512 threads) instead of 64/4. Halves the
// number of M-blocks -> halves fp32 B-panel restaging; staging per thread per
// K-step drops 20 float4 -> 12 (A:4 + B:8). fp32->bf16 cvt stays in-kernel so
// the workspace layout is byte-identical to the proven round-0 layout.
// Block: 128 rows x 256 G-cols (64 channels x 4 gates).
// B-LDS row r <-> Wih row (r>>6)*256 + ch0 + (r&63); n-tile n = gate*4 + cs.
// ---------------------------------------------------------------------------
__global__ __launch_bounds__(512) void xg_gemm(
    const float* __restrict__ X, const float* __restrict__ Wih,
    const float* __restrict__ bias, bf16_t* __restrict__ xg2) {
  __shared__ __align__(16) bf16_t As[128][72];   // 18.4 KB
  __shared__ __align__(16) bf16_t Bs[256][72];   // 36.9 KB

  const int tid = threadIdx.x;
  const int lane = tid & 63;
  const int w = tid >> 6;        // wave 0..7 -> M-rows 16w..16w+15
  const int q = lane >> 4;
  const int l15 = lane & 15;
  const int m0 = blockIdx.x * 128;
  const int ch0 = blockIdx.y * 64;   // channel tile within H

  f32x4 acc[16];
  #pragma unroll
  for (int n = 0; n < 16; ++n) acc[n] = (f32x4){0.f, 0.f, 0.f, 0.f};

  for (int kt = 0; kt < 8; ++kt) {
    const int k0 = kt * 64;
    __syncthreads();
    // A: 2048 float4 slots (128 rows x 16) -> 4 per thread
    #pragma unroll
    for (int i = 0; i < 4; ++i) {
      int f = tid + 512 * i;
      int r = f >> 4, c4 = f & 15;
      float4 va = *(const float4*)(X + (size_t)(m0 + r) * D_ + k0 + c4 * 4);
      *(bf16x4*)&As[r][c4 * 4] =
          (bf16x4){(bf16_t)va.x, (bf16_t)va.y, (bf16_t)va.z, (bf16_t)va.w};
    }
    // B: 4096 float4 slots (256 rows x 16) -> 8 per thread
    #pragma unroll
    for (int j = 0; j < 8; ++j) {
      int f = tid + 512 * j;
      int r = f >> 4, c4 = f & 15;
      int wr = (r >> 6) * 256 + ch0 + (r & 63);
      float4 vb = *(const float4*)(Wih + (size_t)wr * D_ + k0 + c4 * 4);
      *(bf16x4*)&Bs[r][c4 * 4] =
          (bf16x4){(bf16_t)vb.x, (bf16_t)vb.y, (bf16_t)vb.z, (bf16_t)vb.w};
    }
    __syncthreads();
    #pragma unroll
    for (int kk = 0; kk < 2; ++kk) {
      bf16x8 a = *(const bf16x8*)&As[16 * w + l15][kk * 32 + q * 8];
      #pragma unroll
      for (int n = 0; n < 16; ++n) {
        bf16x8 b = *(const bf16x8*)&Bs[16 * n + l15][kk * 32 + q * 8];
        acc[n] = __builtin_amdgcn_mfma_f32_16x16x32_bf16(a, b, acc[n], 0, 0, 0);
      }
    }
  }
  // epilogue: C/D layout col=lane&15, row=quad*4+reg; acc[g*4+cs]
  #pragma unroll
  for (int cs = 0; cs < 4; ++cs) {
    const int cc = ch0 + cs * 16 + l15;
    float bv0 = bias[cc], bv1 = bias[256 + cc];
    float bv2 = bias[512 + cc], bv3 = bias[768 + cc];
    #pragma unroll
    for (int i = 0; i < 4; ++i) {
      int row = m0 + 16 * w + 4 * q + i;
      bf16x4 v = (bf16x4){(bf16_t)(acc[cs][i] + bv0), (bf16_t)(acc[4 + cs][i] + bv1),
                          (bf16_t)(acc[8 + cs][i] + bv2), (bf16_t)(acc[12 + cs][i] + bv3)};
      *(bf16x4*)(xg2 + ((size_t)row * 256 + cc) * 4) = v;
    }
  }
}

// ---------------------------------------------------------------------------
// LSTM scan: 16 WGs x 8 batch rows, 8 waves/WG. W_hh on-chip (48 frags/wave
// in regs + 16 in LDS). MFMA M=16 is half-idle (rows 8..15 stay zero) - the
// deliberate trade: 2x CUs, half the per-CU cell/VALU work.
// After MFMA (C/D: row=4q+i, col=c) gates are redistributed so ALL 64 lanes
// handle 2 cells: lane (q,l15) owns rows {rq, rq+1}, rq=(q&1)*4+(q>>1)*2;
// quads 2,3 pull regs {2,3} from lane^32 via __shfl.
// LDS-only barrier + top-of-step register-double-buffered xg prefetch: global
// prefetches stay in flight across the barrier (no vmcnt(0) drain).
// ---------------------------------------------------------------------------
__global__ __launch_bounds__(512, 2) void lstm_scan(
    const bf16_t* __restrict__ xg2, const bf16_t* __restrict__ Whh,
    float* __restrict__ hT) {
  __shared__ __align__(16) bf16_t wlds[8 * 16 * 512];   // 128 KB
  __shared__ __align__(16) bf16_t hbuf[2][16][264];     // 16.9 KB

  const int tid = threadIdx.x;
  const int lane = tid & 63;
  const int w = tid >> 6;        // wave 0..7
  const int q = lane >> 4;
  const int l15 = lane & 15;
  const int b0 = blockIdx.x * 8;
  const int rq = (q & 1) * 4 + (q >> 1) * 2;   // this lane's row pair {rq,rq+1}
  const bool hi = (lane >= 32);                 // quads 2,3 pull from lane^32

  // ---- load W_hh: 6 (p,gate) sets -> VGPRs, (p=1, g=2,3) -> LDS ----
  bf16x8 wreg[6][8];
  #pragma unroll
  for (int p2 = 0; p2 < 2; ++p2) {
    #pragma unroll
    for (int g2 = 0; g2 < 4; ++g2) {
      const int j = p2 * 4 + g2;
      const bf16_t* src =
          Whh + (size_t)(g2 * 256 + 32 * w + 16 * p2 + l15) * H_ + q * 8;
      #pragma unroll
      for (int kk = 0; kk < 8; ++kk) {
        bf16x8 v = *(const bf16x8*)(src + kk * 32);
        if (j < 6) {
          wreg[j][kk] = v;
        } else {
          *(bf16x8*)&wlds[(size_t)((w * 16 + (g2 - 2) * 8 + kk)) * 512 + lane * 8] = v;
        }
      }
    }
  }

  for (int i = tid; i < 2 * 16 * 264; i += 512) ((bf16_t*)hbuf)[i] = (bf16_t)0.0f;
  __syncthreads();

  float cst[2][2];
  #pragma unroll
  for (int p = 0; p < 2; ++p) { cst[p][0] = 0.f; cst[p][1] = 0.f; }

  // xg pointers [phase][cell]; elem idx = row_g*T*1024 + t*1024 + c*4
  const bf16_t* xp[2][2];
  #pragma unroll
  for (int p = 0; p < 2; ++p)
    #pragma unroll
    for (int k = 0; k < 2; ++k)
      xp[p][k] = xg2 + (size_t)(b0 + rq + k) * (size_t)T_ * 1024 + (32 * w + 16 * p + l15) * 4;

  bf16x4 xv[2][2], xn[2][2];
  #pragma unroll
  for (int p = 0; p < 2; ++p)
    #pragma unroll
    for (int k = 0; k < 2; ++k) {
      xv[p][k] = *(const bf16x4*)xp[p][k];   // t=0
      xp[p][k] += 1024;                       // point at t=1
    }

  auto step = [&](int t, bf16x4 (&xc)[2][2], bf16x4 (&xf)[2][2]) {
    // prefetch t+1 at TOP of step (in flight across this step's barrier).
    // Last iter (t=1023) reads 2 KB past xg2 end -> lands in whhb region, unused.
    #pragma unroll
    for (int p = 0; p < 2; ++p)
      #pragma unroll
      for (int k = 0; k < 2; ++k) {
        xf[p][k] = *(const bf16x4*)xp[p][k];
        xp[p][k] += 1024;
      }
    const int cur = t & 1;
    #pragma unroll
    for (int p = 0; p < 2; ++p) {
      f32x4 acc[4];
      #pragma unroll
      for (int g = 0; g < 4; ++g) acc[g] = (f32x4){0.f, 0.f, 0.f, 0.f};
      #pragma unroll
      for (int kk = 0; kk < 8; ++kk) {
        bf16x8 a = *(const bf16x8*)&hbuf[cur][l15][kk * 32 + q * 8];
        if (p == 0) {
          acc[0] = __builtin_amdgcn_mfma_f32_16x16x32_bf16(a, wreg[0][kk], acc[0], 0, 0, 0);
          acc[1] = __builtin_amdgcn_mfma_f32_16x16x32_bf16(a, wreg[1][kk], acc[1], 0, 0, 0);
          acc[2] = __builtin_amdgcn_mfma_f32_16x16x32_bf16(a, wreg[2][kk], acc[2], 0, 0, 0);
          acc[3] = __builtin_amdgcn_mfma_f32_16x16x32_bf16(a, wreg[3][kk], acc[3], 0, 0, 0);
        } else {
          acc[0] = __builtin_amdgcn_mfma_f32_16x16x32_bf16(a, wreg[4][kk], acc[0], 0, 0, 0);
          acc[1] = __builtin_amdgcn_mfma_f32_16x16x32_bf16(a, wreg[5][kk], acc[1], 0, 0, 0);
          bf16x8 bg = *(const bf16x8*)&wlds[(size_t)(w * 16 + kk) * 512 + lane * 8];
          bf16x8 bo = *(const bf16x8*)&wlds[(size_t)(w * 16 + 8 + kk) * 512 + lane * 8];
          acc[2] = __builtin_amdgcn_mfma_f32_16x16x32_bf16(a, bg, acc[2], 0, 0, 0);
          acc[3] = __builtin_amdgcn_mfma_f32_16x16x32_bf16(a, bo, acc[3], 0, 0, 0);
        }
      }
      // redistribute: every lane ends with 2 cells (rows rq, rq+1)
      float G0[4], G1[4];
      #pragma unroll
      for (int g = 0; g < 4; ++g) {
        float s2 = __shfl(acc[g][2], lane ^ 32, 64);
        float s3 = __shfl(acc[g][3], lane ^ 32, 64);
        G0[g] = hi ? s2 : acc[g][0];
        G1[g] = hi ? s3 : acc[g][1];
      }
      const int c = 32 * w + 16 * p + l15;
      #pragma unroll
      for (int k = 0; k < 2; ++k) {
        const float* Gv_ = k ? G1 : G0;
        float gi = Gv_[0] + (float)xc[p][k][0];
        float gf = Gv_[1] + (float)xc[p][k][1];
        float gg = Gv_[2] + (float)xc[p][k][2];
        float go = Gv_[3] + (float)xc[p][k][3];
        float I = sigmoid_f(gi);
        float F = sigmoid_f(gf);
        float Gg = tanh_f(gg);
        float Ov = sigmoid_f(go);
        float cv = F * cst[p][k] + I * Gg;
        cst[p][k] = cv;
        float hv = Ov * tanh_f(cv);
        hbuf[cur ^ 1][rq + k][c] = (bf16_t)hv;
        if (t == T_ - 1) hT[(size_t)(b0 + rq + k) * H_ + c] = hv;
      }
    }
    barrier_lds_only();
  };

  #pragma unroll 1
  for (int t = 0; t < T_; t += 2) {
    step(t, xv, xn);
    step(t + 1, xn, xv);
  }
}

// ---------------------------------------------------------------------------
// out = h_T @ W_out^T + b_out   [128,256]x[256,128] -> tiny
// ---------------------------------------------------------------------------
__global__ __launch_bounds__(128) void head_gemm(
    const float* __restrict__ hT, const float* __restrict__ Wout,
    const float* __restrict__ bout, float* __restrict__ out) {
  __shared__ float hrow[H_];
  const int b = blockIdx.x;
  const int o = threadIdx.x;
  hrow[o] = hT[(size_t)b * H_ + o];
  hrow[o + 128] = hT[(size_t)b * H_ + 128 + o];
  __syncthreads();
  float s = bout[o];
  const float* wr = Wout + (size_t)o * H_;
  #pragma unroll 8
  for (int j = 0; j < H_; ++j) s += hrow[j] * wr[j];
  out[(size_t)b * 128 + o] = s;
}

// ---------------------------------------------------------------------------
extern "C" void kernel_launch(void* const* d_in, const int* in_sizes, int n_in,
                              void* d_out, int out_size, void* d_ws, size_t ws_size,
                              hipStream_t stream) {
  const float* X    = (const float*)d_in[0];
  const float* Wih  = (const float*)d_in[1];
  const float* Whh  = (const float*)d_in[2];
  const float* bih  = (const float*)d_in[3];
  const float* bhh  = (const float*)d_in[4];
  const float* Wout = (const float*)d_in[5];
  const float* bout = (const float*)d_in[6];
  float* out = (float*)d_out;

  // workspace layout (bytes) — byte-identical to the proven round-0 layout
  char* ws = (char*)d_ws;
  const size_t XG_BYTES   = (size_t)B_ * T_ * G_ * 2;        // 268435456
  const size_t WHHB_BYTES = (size_t)G_ * H_ * 2;             // 524288 (also prefetch slack)
  const size_t BIAS_BYTES = (size_t)G_ * 4;                  // 4096
  bf16_t* xg2  = (bf16_t*)ws;
  bf16_t* whhb = (bf16_t*)(ws + XG_BYTES);
  float*  bias = (float*)(ws + XG_BYTES + WHHB_BYTES);
  float*  hT   = (float*)(ws + XG_BYTES + WHHB_BYTES + BIAS_BYTES);

  prep_kernel<<<dim3(1024), 256, 0, stream>>>(Whh, bih, bhh, whhb, bias);
  xg_gemm<<<dim3((B_ * T_) / 128, 4), 512, 0, stream>>>(X, Wih, bias, xg2);
  lstm_scan<<<dim3(B_ / 8), 512, 0, stream>>>(xg2, whhb, hT);
  head_gemm<<<dim3(B_), 128, 0, stream>>>(hT, Wout, bout, out);
}

// Round 4
// 3178.505 us; speedup vs baseline: 1.2088x; 1.0499x over previous
//
#include <hip/hip_runtime.h>
#include <hip/hip_bf16.h>

// Problem constants
#define B_ 128
#define T_ 1024
#define D_ 512
#define H_ 256
#define G_ 1024   // 4*H

typedef __bf16 bf16_t;
typedef __bf16 bf16x8 __attribute__((ext_vector_type(8)));
typedef __bf16 bf16x4 __attribute__((ext_vector_type(4)));
typedef float  f32x4  __attribute__((ext_vector_type(4)));

__device__ __forceinline__ float fast_rcp(float x) { return __builtin_amdgcn_rcpf(x); }

__device__ __forceinline__ float sigmoid_f(float x) {
  return fast_rcp(1.0f + __expf(-x));
}
__device__ __forceinline__ float tanh_f(float x) {
  x = fminf(fmaxf(x, -15.0f), 15.0f);   // avoid inf/inf NaN
  float e = __expf(-2.0f * x);
  return (1.0f - e) * fast_rcp(1.0f + e);
}

// Workgroup barrier that waits only on LDS ops (lgkmcnt).
__device__ __forceinline__ void barrier_lds_only() {
  asm volatile("s_waitcnt lgkmcnt(0)\n\ts_barrier" ::: "memory");
}

// global -> LDS direct copy, 16B per lane. LDS dest must be the wave-uniform
// chunk base (HW adds lane*16); global src is per-lane.
__device__ __forceinline__ void gload_lds16(const void* g, void* l) {
  __builtin_amdgcn_global_load_lds(
      (const __attribute__((address_space(1))) void*)g,
      (__attribute__((address_space(3))) void*)l, 16, 0, 0);
}

// ---------------------------------------------------------------------------
// prep (slow path): W_hh fp32 -> bf16, bias = b_ih + b_hh
// ---------------------------------------------------------------------------
__global__ __launch_bounds__(256) void prep_kernel(
    const float* __restrict__ Whh, const float* __restrict__ bih,
    const float* __restrict__ bhh, bf16_t* __restrict__ whhb,
    float* __restrict__ bias) {
  int i = blockIdx.x * 256 + threadIdx.x;
  if (i < G_ * H_) whhb[i] = (bf16_t)Whh[i];
  if (i < G_) bias[i] = bih[i] + bhh[i];
}

// prep (fast path): also W_ih fp32 -> bf16. Grid 2048x256 = 524288 = G_*D_.
__global__ __launch_bounds__(256) void prep_full_kernel(
    const float* __restrict__ Whh, const float* __restrict__ bih,
    const float* __restrict__ bhh, const float* __restrict__ Wih,
    bf16_t* __restrict__ whhb, bf16_t* __restrict__ wihb,
    float* __restrict__ bias) {
  int i = blockIdx.x * 256 + threadIdx.x;
  if (i < G_ * H_) whhb[i] = (bf16_t)Whh[i];
  wihb[i] = (bf16_t)Wih[i];          // i < G_*D_ == gridDim*256 exactly
  if (i < G_) bias[i] = bih[i] + bhh[i];
}

// ---------------------------------------------------------------------------
// X fp32 [B,T,D] -> bf16 (fast path only). 134 MB result fits in 256 MB L3,
// so xg_gemm_fast's 4x A re-read (one per ch-tile) is L3-resident.
// ---------------------------------------------------------------------------
__global__ __launch_bounds__(256) void xconv_kernel(
    const float* __restrict__ X, bf16_t* __restrict__ Xb) {
  const int n4 = (B_ * T_ * D_) / 4;
  const int stride = gridDim.x * 256;
  for (int i = blockIdx.x * 256 + threadIdx.x; i < n4; i += stride) {
    float4 v = ((const float4*)X)[i];
    ((bf16x4*)Xb)[i] =
        (bf16x4){(bf16_t)v.x, (bf16_t)v.y, (bf16_t)v.z, (bf16_t)v.w};
  }
}

// ---------------------------------------------------------------------------
// FAST xg_gemm: bf16 inputs, global_load_lds staging (zero staging VALU).
// 128 rows x 256 G-cols per block, 8 waves, linear LDS (48 KB -> 3 blocks/CU).
// Same fragment math / epilogue as the verified VALU-staged version.
// B-LDS row r <-> Wihb row (r>>6)*256 + ch0 + (r&63).
// ---------------------------------------------------------------------------
__global__ __launch_bounds__(512) void xg_gemm_fast(
    const bf16_t* __restrict__ Xb, const bf16_t* __restrict__ Wihb,
    const float* __restrict__ bias, bf16_t* __restrict__ xg2) {
  __shared__ __align__(16) bf16_t As[128][64];   // 16 KB, linear (gload_lds)
  __shared__ __align__(16) bf16_t Bs[256][64];   // 32 KB, linear

  const int tid = threadIdx.x;
  const int lane = tid & 63;
  const int w = tid >> 6;        // wave 0..7 -> M-rows 16w..16w+15
  const int q = lane >> 4;
  const int l15 = lane & 15;
  const int m0 = blockIdx.x * 128;
  const int ch0 = blockIdx.y * 64;

  // per-lane source coords within an 8-row x 64-col (1 KB) chunk
  const int lr = lane >> 3;          // row within chunk 0..7
  const int lc = (lane & 7) * 8;     // bf16 col offset 0..56

  f32x4 acc[16];
  #pragma unroll
  for (int n = 0; n < 16; ++n) acc[n] = (f32x4){0.f, 0.f, 0.f, 0.f};

  for (int kt = 0; kt < 8; ++kt) {
    const int k0 = kt * 64;
    __syncthreads();   // previous compute done before overwrite
    // A: 16 chunks of 8 rows -> 2 per wave
    #pragma unroll
    for (int j = 0; j < 2; ++j) {
      const int c = w * 2 + j;
      gload_lds16(Xb + (size_t)(m0 + c * 8 + lr) * D_ + k0 + lc,
                  (char*)&As[0][0] + c * 1024);
    }
    // B: 32 chunks of 8 rows -> 4 per wave
    #pragma unroll
    for (int j = 0; j < 4; ++j) {
      const int c = w * 4 + j;
      const int br = c * 8 + lr;
      const int wr = (br >> 6) * 256 + ch0 + (br & 63);
      gload_lds16(Wihb + (size_t)wr * D_ + k0 + lc,
                  (char*)&Bs[0][0] + c * 1024);
    }
    __syncthreads();   // drains vmcnt(0): staged data visible
    #pragma unroll
    for (int kk = 0; kk < 2; ++kk) {
      bf16x8 a = *(const bf16x8*)&As[16 * w + l15][kk * 32 + q * 8];
      #pragma unroll
      for (int n = 0; n < 16; ++n) {
        bf16x8 b = *(const bf16x8*)&Bs[16 * n + l15][kk * 32 + q * 8];
        acc[n] = __builtin_amdgcn_mfma_f32_16x16x32_bf16(a, b, acc[n], 0, 0, 0);
      }
    }
  }
  // epilogue: C/D layout col=lane&15, row=quad*4+reg; acc[g*4+cs]
  #pragma unroll
  for (int cs = 0; cs < 4; ++cs) {
    const int cc = ch0 + cs * 16 + l15;
    float bv0 = bias[cc], bv1 = bias[256 + cc];
    float bv2 = bias[512 + cc], bv3 = bias[768 + cc];
    #pragma unroll
    for (int i = 0; i < 4; ++i) {
      int row = m0 + 16 * w + 4 * q + i;
      bf16x4 v = (bf16x4){(bf16_t)(acc[cs][i] + bv0), (bf16_t)(acc[4 + cs][i] + bv1),
                          (bf16_t)(acc[8 + cs][i] + bv2), (bf16_t)(acc[12 + cs][i] + bv3)};
      *(bf16x4*)(xg2 + ((size_t)row * 256 + cc) * 4) = v;
    }
  }
}

// ---------------------------------------------------------------------------
// SLOW xg_gemm (fallback, proven round-3): fp32 inputs, VALU staging.
// ---------------------------------------------------------------------------
__global__ __launch_bounds__(512) void xg_gemm(
    const float* __restrict__ X, const float* __restrict__ Wih,
    const float* __restrict__ bias, bf16_t* __restrict__ xg2) {
  __shared__ __align__(16) bf16_t As[128][72];
  __shared__ __align__(16) bf16_t Bs[256][72];

  const int tid = threadIdx.x;
  const int lane = tid & 63;
  const int w = tid >> 6;
  const int q = lane >> 4;
  const int l15 = lane & 15;
  const int m0 = blockIdx.x * 128;
  const int ch0 = blockIdx.y * 64;

  f32x4 acc[16];
  #pragma unroll
  for (int n = 0; n < 16; ++n) acc[n] = (f32x4){0.f, 0.f, 0.f, 0.f};

  for (int kt = 0; kt < 8; ++kt) {
    const int k0 = kt * 64;
    __syncthreads();
    #pragma unroll
    for (int i = 0; i < 4; ++i) {
      int f = tid + 512 * i;
      int r = f >> 4, c4 = f & 15;
      float4 va = *(const float4*)(X + (size_t)(m0 + r) * D_ + k0 + c4 * 4);
      *(bf16x4*)&As[r][c4 * 4] =
          (bf16x4){(bf16_t)va.x, (bf16_t)va.y, (bf16_t)va.z, (bf16_t)va.w};
    }
    #pragma unroll
    for (int j = 0; j < 8; ++j) {
      int f = tid + 512 * j;
      int r = f >> 4, c4 = f & 15;
      int wr = (r >> 6) * 256 + ch0 + (r & 63);
      float4 vb = *(const float4*)(Wih + (size_t)wr * D_ + k0 + c4 * 4);
      *(bf16x4*)&Bs[r][c4 * 4] =
          (bf16x4){(bf16_t)vb.x, (bf16_t)vb.y, (bf16_t)vb.z, (bf16_t)vb.w};
    }
    __syncthreads();
    #pragma unroll
    for (int kk = 0; kk < 2; ++kk) {
      bf16x8 a = *(const bf16x8*)&As[16 * w + l15][kk * 32 + q * 8];
      #pragma unroll
      for (int n = 0; n < 16; ++n) {
        bf16x8 b = *(const bf16x8*)&Bs[16 * n + l15][kk * 32 + q * 8];
        acc[n] = __builtin_amdgcn_mfma_f32_16x16x32_bf16(a, b, acc[n], 0, 0, 0);
      }
    }
  }
  #pragma unroll
  for (int cs = 0; cs < 4; ++cs) {
    const int cc = ch0 + cs * 16 + l15;
    float bv0 = bias[cc], bv1 = bias[256 + cc];
    float bv2 = bias[512 + cc], bv3 = bias[768 + cc];
    #pragma unroll
    for (int i = 0; i < 4; ++i) {
      int row = m0 + 16 * w + 4 * q + i;
      bf16x4 v = (bf16x4){(bf16_t)(acc[cs][i] + bv0), (bf16_t)(acc[4 + cs][i] + bv1),
                          (bf16_t)(acc[8 + cs][i] + bv2), (bf16_t)(acc[12 + cs][i] + bv3)};
      *(bf16x4*)(xg2 + ((size_t)row * 256 + cc) * 4) = v;
    }
  }
}

// ---------------------------------------------------------------------------
// LSTM scan (unchanged, verified): 16 WGs x 8 batch rows, 8 waves/WG.
// ---------------------------------------------------------------------------
__global__ __launch_bounds__(512, 2) void lstm_scan(
    const bf16_t* __restrict__ xg2, const bf16_t* __restrict__ Whh,
    float* __restrict__ hT) {
  __shared__ __align__(16) bf16_t wlds[8 * 16 * 512];   // 128 KB
  __shared__ __align__(16) bf16_t hbuf[2][16][264];     // 16.9 KB

  const int tid = threadIdx.x;
  const int lane = tid & 63;
  const int w = tid >> 6;
  const int q = lane >> 4;
  const int l15 = lane & 15;
  const int b0 = blockIdx.x * 8;
  const int rq = (q & 1) * 4 + (q >> 1) * 2;
  const bool hi = (lane >= 32);

  bf16x8 wreg[6][8];
  #pragma unroll
  for (int p2 = 0; p2 < 2; ++p2) {
    #pragma unroll
    for (int g2 = 0; g2 < 4; ++g2) {
      const int j = p2 * 4 + g2;
      const bf16_t* src =
          Whh + (size_t)(g2 * 256 + 32 * w + 16 * p2 + l15) * H_ + q * 8;
      #pragma unroll
      for (int kk = 0; kk < 8; ++kk) {
        bf16x8 v = *(const bf16x8*)(src + kk * 32);
        if (j < 6) {
          wreg[j][kk] = v;
        } else {
          *(bf16x8*)&wlds[(size_t)((w * 16 + (g2 - 2) * 8 + kk)) * 512 + lane * 8] = v;
        }
      }
    }
  }

  for (int i = tid; i < 2 * 16 * 264; i += 512) ((bf16_t*)hbuf)[i] = (bf16_t)0.0f;
  __syncthreads();

  float cst[2][2];
  #pragma unroll
  for (int p = 0; p < 2; ++p) { cst[p][0] = 0.f; cst[p][1] = 0.f; }

  const bf16_t* xp[2][2];
  #pragma unroll
  for (int p = 0; p < 2; ++p)
    #pragma unroll
    for (int k = 0; k < 2; ++k)
      xp[p][k] = xg2 + (size_t)(b0 + rq + k) * (size_t)T_ * 1024 + (32 * w + 16 * p + l15) * 4;

  bf16x4 xv[2][2], xn[2][2];
  #pragma unroll
  for (int p = 0; p < 2; ++p)
    #pragma unroll
    for (int k = 0; k < 2; ++k) {
      xv[p][k] = *(const bf16x4*)xp[p][k];
      xp[p][k] += 1024;
    }

  auto step = [&](int t, bf16x4 (&xc)[2][2], bf16x4 (&xf)[2][2]) {
    #pragma unroll
    for (int p = 0; p < 2; ++p)
      #pragma unroll
      for (int k = 0; k < 2; ++k) {
        xf[p][k] = *(const bf16x4*)xp[p][k];
        xp[p][k] += 1024;
      }
    const int cur = t & 1;
    #pragma unroll
    for (int p = 0; p < 2; ++p) {
      f32x4 acc[4];
      #pragma unroll
      for (int g = 0; g < 4; ++g) acc[g] = (f32x4){0.f, 0.f, 0.f, 0.f};
      #pragma unroll
      for (int kk = 0; kk < 8; ++kk) {
        bf16x8 a = *(const bf16x8*)&hbuf[cur][l15][kk * 32 + q * 8];
        if (p == 0) {
          acc[0] = __builtin_amdgcn_mfma_f32_16x16x32_bf16(a, wreg[0][kk], acc[0], 0, 0, 0);
          acc[1] = __builtin_amdgcn_mfma_f32_16x16x32_bf16(a, wreg[1][kk], acc[1], 0, 0, 0);
          acc[2] = __builtin_amdgcn_mfma_f32_16x16x32_bf16(a, wreg[2][kk], acc[2], 0, 0, 0);
          acc[3] = __builtin_amdgcn_mfma_f32_16x16x32_bf16(a, wreg[3][kk], acc[3], 0, 0, 0);
        } else {
          acc[0] = __builtin_amdgcn_mfma_f32_16x16x32_bf16(a, wreg[4][kk], acc[0], 0, 0, 0);
          acc[1] = __builtin_amdgcn_mfma_f32_16x16x32_bf16(a, wreg[5][kk], acc[1], 0, 0, 0);
          bf16x8 bg = *(const bf16x8*)&wlds[(size_t)(w * 16 + kk) * 512 + lane * 8];
          bf16x8 bo = *(const bf16x8*)&wlds[(size_t)(w * 16 + 8 + kk) * 512 + lane * 8];
          acc[2] = __builtin_amdgcn_mfma_f32_16x16x32_bf16(a, bg, acc[2], 0, 0, 0);
          acc[3] = __builtin_amdgcn_mfma_f32_16x16x32_bf16(a, bo, acc[3], 0, 0, 0);
        }
      }
      float G0[4], G1[4];
      #pragma unroll
      for (int g = 0; g < 4; ++g) {
        float s2 = __shfl(acc[g][2], lane ^ 32, 64);
        float s3 = __shfl(acc[g][3], lane ^ 32, 64);
        G0[g] = hi ? s2 : acc[g][0];
        G1[g] = hi ? s3 : acc[g][1];
      }
      const int c = 32 * w + 16 * p + l15;
      #pragma unroll
      for (int k = 0; k < 2; ++k) {
        const float* Gv_ = k ? G1 : G0;
        float gi = Gv_[0] + (float)xc[p][k][0];
        float gf = Gv_[1] + (float)xc[p][k][1];
        float gg = Gv_[2] + (float)xc[p][k][2];
        float go = Gv_[3] + (float)xc[p][k][3];
        float I = sigmoid_f(gi);
        float F = sigmoid_f(gf);
        float Gg = tanh_f(gg);
        float Ov = sigmoid_f(go);
        float cv = F * cst[p][k] + I * Gg;
        cst[p][k] = cv;
        float hv = Ov * tanh_f(cv);
        hbuf[cur ^ 1][rq + k][c] = (bf16_t)hv;
        if (t == T_ - 1) hT[(size_t)(b0 + rq + k) * H_ + c] = hv;
      }
    }
    barrier_lds_only();
  };

  #pragma unroll 1
  for (int t = 0; t < T_; t += 2) {
    step(t, xv, xn);
    step(t + 1, xn, xv);
  }
}

// ---------------------------------------------------------------------------
// out = h_T @ W_out^T + b_out
// ---------------------------------------------------------------------------
__global__ __launch_bounds__(128) void head_gemm(
    const float* __restrict__ hT, const float* __restrict__ Wout,
    const float* __restrict__ bout, float* __restrict__ out) {
  __shared__ float hrow[H_];
  const int b = blockIdx.x;
  const int o = threadIdx.x;
  hrow[o] = hT[(size_t)b * H_ + o];
  hrow[o + 128] = hT[(size_t)b * H_ + 128 + o];
  __syncthreads();
  float s = bout[o];
  const float* wr = Wout + (size_t)o * H_;
  #pragma unroll 8
  for (int j = 0; j < H_; ++j) s += hrow[j] * wr[j];
  out[(size_t)b * 128 + o] = s;
}

// ---------------------------------------------------------------------------
extern "C" void kernel_launch(void* const* d_in, const int* in_sizes, int n_in,
                              void* d_out, int out_size, void* d_ws, size_t ws_size,
                              hipStream_t stream) {
  const float* X    = (const float*)d_in[0];
  const float* Wih  = (const float*)d_in[1];
  const float* Whh  = (const float*)d_in[2];
  const float* bih  = (const float*)d_in[3];
  const float* bhh  = (const float*)d_in[4];
  const float* Wout = (const float*)d_in[5];
  const float* bout = (const float*)d_in[6];
  float* out = (float*)d_out;

  // workspace layout (bytes). Prefix is byte-identical to the proven layout;
  // wihb/xb exist only on the fast path, gated on ws_size.
  char* ws = (char*)d_ws;
  const size_t XG_BYTES   = (size_t)B_ * T_ * G_ * 2;   // 268435456
  const size_t WHHB_BYTES = (size_t)G_ * H_ * 2;        // 524288
  const size_t BIAS_BYTES = (size_t)G_ * 4;             // 4096
  const size_t HT_BYTES   = (size_t)B_ * H_ * 4;        // 131072
  const size_t WIHB_BYTES = (size_t)G_ * D_ * 2;        // 1048576
  const size_t XB_BYTES   = (size_t)B_ * T_ * D_ * 2;   // 134217728
  bf16_t* xg2  = (bf16_t*)ws;
  bf16_t* whhb = (bf16_t*)(ws + XG_BYTES);
  float*  bias = (float*)(ws + XG_BYTES + WHHB_BYTES);
  float*  hT   = (float*)(ws + XG_BYTES + WHHB_BYTES + BIAS_BYTES);
  bf16_t* wihb = (bf16_t*)(ws + XG_BYTES + WHHB_BYTES + BIAS_BYTES + HT_BYTES);
  bf16_t* xb   = (bf16_t*)(ws + XG_BYTES + WHHB_BYTES + BIAS_BYTES + HT_BYTES + WIHB_BYTES);

  const size_t NEED_FAST =
      XG_BYTES + WHHB_BYTES + BIAS_BYTES + HT_BYTES + WIHB_BYTES + XB_BYTES;

  if (ws_size >= NEED_FAST) {
    prep_full_kernel<<<dim3(2048), 256, 0, stream>>>(Whh, bih, bhh, Wih, whhb, wihb, bias);
    xconv_kernel<<<dim3(4096), 256, 0, stream>>>(X, xb);
    xg_gemm_fast<<<dim3((B_ * T_) / 128, 4), 512, 0, stream>>>(xb, wihb, bias, xg2);
  } else {
    prep_kernel<<<dim3(1024), 256, 0, stream>>>(Whh, bih, bhh, whhb, bias);
    xg_gemm<<<dim3((B_ * T_) / 128, 4), 512, 0, stream>>>(X, Wih, bias, xg2);
  }
  lstm_scan<<<dim3(B_ / 8), 512, 0, stream>>>(xg2, whhb, hT);
  head_gemm<<<dim3(B_), 128, 0, stream>>>(hT, Wout, bout, out);
}

// Round 5
// 3109.919 us; speedup vs baseline: 1.2354x; 1.0221x over previous
//
#include <hip/hip_runtime.h>
#include <hip/hip_bf16.h>

// Problem constants
#define B_ 128
#define T_ 1024
#define D_ 512
#define H_ 256
#define G_ 1024   // 4*H

typedef __bf16 bf16_t;
typedef __bf16 bf16x8 __attribute__((ext_vector_type(8)));
typedef __bf16 bf16x4 __attribute__((ext_vector_type(4)));
typedef float  f32x4  __attribute__((ext_vector_type(4)));

__device__ __forceinline__ float fast_rcp(float x) { return __builtin_amdgcn_rcpf(x); }

__device__ __forceinline__ float sigmoid_f(float x) {
  return fast_rcp(1.0f + __expf(-x));
}
__device__ __forceinline__ float tanh_f(float x) {
  x = fminf(fmaxf(x, -15.0f), 15.0f);   // avoid inf/inf NaN
  float e = __expf(-2.0f * x);
  return (1.0f - e) * fast_rcp(1.0f + e);
}

// Workgroup barrier that waits only on LDS ops (lgkmcnt).
__device__ __forceinline__ void barrier_lds_only() {
  asm volatile("s_waitcnt lgkmcnt(0)\n\ts_barrier" ::: "memory");
}

// global -> LDS direct copy, 16B per lane. LDS dest must be the wave-uniform
// chunk base (HW adds lane*16); global src is per-lane.
__device__ __forceinline__ void gload_lds16(const void* g, void* l) {
  __builtin_amdgcn_global_load_lds(
      (const __attribute__((address_space(1))) void*)g,
      (__attribute__((address_space(3))) void*)l, 16, 0, 0);
}

// ---------------------------------------------------------------------------
// prep (slow path): W_hh fp32 -> bf16, bias = b_ih + b_hh
// ---------------------------------------------------------------------------
__global__ __launch_bounds__(256) void prep_kernel(
    const float* __restrict__ Whh, const float* __restrict__ bih,
    const float* __restrict__ bhh, bf16_t* __restrict__ whhb,
    float* __restrict__ bias) {
  int i = blockIdx.x * 256 + threadIdx.x;
  if (i < G_ * H_) whhb[i] = (bf16_t)Whh[i];
  if (i < G_) bias[i] = bih[i] + bhh[i];
}

// prep (fast path): also W_ih fp32 -> bf16. Grid 2048x256 = 524288 = G_*D_.
__global__ __launch_bounds__(256) void prep_full_kernel(
    const float* __restrict__ Whh, const float* __restrict__ bih,
    const float* __restrict__ bhh, const float* __restrict__ Wih,
    bf16_t* __restrict__ whhb, bf16_t* __restrict__ wihb,
    float* __restrict__ bias) {
  int i = blockIdx.x * 256 + threadIdx.x;
  if (i < G_ * H_) whhb[i] = (bf16_t)Whh[i];
  wihb[i] = (bf16_t)Wih[i];          // i < G_*D_ == gridDim*256 exactly
  if (i < G_) bias[i] = bih[i] + bhh[i];
}

// ---------------------------------------------------------------------------
// X fp32 [B,T,D] -> bf16 (fast path only). 134 MB result ~L3-resident.
// ---------------------------------------------------------------------------
__global__ __launch_bounds__(256) void xconv_kernel(
    const float* __restrict__ X, bf16_t* __restrict__ Xb) {
  const int n4 = (B_ * T_ * D_) / 4;
  const int stride = gridDim.x * 256;
  for (int i = blockIdx.x * 256 + threadIdx.x; i < n4; i += stride) {
    float4 v = ((const float4*)X)[i];
    ((bf16x4*)Xb)[i] =
        (bf16x4){(bf16_t)v.x, (bf16_t)v.y, (bf16_t)v.z, (bf16_t)v.w};
  }
}

// ---------------------------------------------------------------------------
// FAST xg_gemm v2: bf16 inputs, global_load_lds staging, 2x4 wave grid
// (wave tile 64 rows x 64 cols: 4 A-frag + 4 B-frag reads per kk for 16 MFMA
// -> 2 MFMA/ds_read, 2.1x less LDS traffic than the 16x256-per-wave v1), and
// XOR bank-swizzle applied BOTH sides (rule #21): LDS dest stays linear,
// global source column is pre-swizzled per lane, fragment reads apply the
// same XOR. Kills the 16-way stride-128B conflicts of linear [128][64].
//   logical (row, slot) lives at physical slot ^ (row & 7)   [slot = 16B col]
// Wave wn owns channel-slice cs=wn for ALL 4 gates (gate = nf) -> packed
// bf16x4 gamma store epilogue unchanged.
// B-LDS row r <-> Wihb row (r>>6)*256 + ch0 + (r&63)  [r = gate*64 + ch-ch0]
// ---------------------------------------------------------------------------
__global__ __launch_bounds__(512) void xg_gemm_fast(
    const bf16_t* __restrict__ Xb, const bf16_t* __restrict__ Wihb,
    const float* __restrict__ bias, bf16_t* __restrict__ xg2) {
  __shared__ __align__(16) bf16_t As[128][64];   // 16 KB, linear (gload_lds)
  __shared__ __align__(16) bf16_t Bs[256][64];   // 32 KB, linear

  const int tid = threadIdx.x;
  const int lane = tid & 63;
  const int w = tid >> 6;        // wave 0..7
  const int wm = w >> 2;         // wave M-slot 0..1 -> rows 64*wm..+63
  const int wn = w & 3;          // wave N-slot 0..3 -> channel slice cs=wn
  const int q = lane >> 4;
  const int l15 = lane & 15;
  const int m0 = blockIdx.x * 128;
  const int ch0 = blockIdx.y * 64;

  // staging: per-lane source coords within an 8-row x 64-col (1 KB) chunk.
  // Physical LDS slot for lane = lane&7; it must hold logical slot
  // (lane&7)^(row&7), row&7 = (lane>>3)&7.  XOR is a bijection per row.
  const int lr = lane >> 3;                      // row within chunk 0..7
  const int ls = (lane & 7) ^ (lr & 7);          // swizzled logical slot
  const int lc = ls * 8;                         // bf16 col offset

  f32x4 acc[4][4];
  #pragma unroll
  for (int mi = 0; mi < 4; ++mi)
    #pragma unroll
    for (int nf = 0; nf < 4; ++nf) acc[mi][nf] = (f32x4){0.f, 0.f, 0.f, 0.f};

  const char* As0 = (const char*)&As[0][0];
  const char* Bs0 = (const char*)&Bs[0][0];

  for (int kt = 0; kt < 8; ++kt) {
    const int k0 = kt * 64;
    __syncthreads();   // previous compute done before overwrite
    // A: 16 chunks of 8 rows -> 2 per wave
    #pragma unroll
    for (int j = 0; j < 2; ++j) {
      const int c = w * 2 + j;
      gload_lds16(Xb + (size_t)(m0 + c * 8 + lr) * D_ + k0 + lc,
                  (char*)&As[0][0] + c * 1024);
    }
    // B: 32 chunks of 8 rows -> 4 per wave
    #pragma unroll
    for (int j = 0; j < 4; ++j) {
      const int c = w * 4 + j;
      const int br = c * 8 + lr;
      const int wr = (br >> 6) * 256 + ch0 + (br & 63);
      gload_lds16(Wihb + (size_t)wr * D_ + k0 + lc,
                  (char*)&Bs[0][0] + c * 1024);
    }
    __syncthreads();   // drains vmcnt(0): staged data visible
    #pragma unroll
    for (int kk = 0; kk < 2; ++kk) {
      bf16x8 a[4], b[4];
      #pragma unroll
      for (int mi = 0; mi < 4; ++mi) {
        const int row = wm * 64 + mi * 16 + l15;
        a[mi] = *(const bf16x8*)(As0 + row * 128 +
                                 (((kk * 4 + q) ^ (row & 7)) * 16));
      }
      #pragma unroll
      for (int nf = 0; nf < 4; ++nf) {
        const int row = nf * 64 + wn * 16 + l15;   // gate nf, cs=wn
        b[nf] = *(const bf16x8*)(Bs0 + row * 128 +
                                 (((kk * 4 + q) ^ (row & 7)) * 16));
      }
      #pragma unroll
      for (int mi = 0; mi < 4; ++mi)
        #pragma unroll
        for (int nf = 0; nf < 4; ++nf)
          acc[mi][nf] =
              __builtin_amdgcn_mfma_f32_16x16x32_bf16(a[mi], b[nf], acc[mi][nf], 0, 0, 0);
    }
  }
  // epilogue: C/D layout col=l15, row=4q+i. col of b[nf] tile = channel
  // ch0 + wn*16 + l15 with gate nf -> pack 4 gates per bf16x4 store.
  const int cc = ch0 + wn * 16 + l15;
  const float bv0 = bias[cc], bv1 = bias[256 + cc];
  const float bv2 = bias[512 + cc], bv3 = bias[768 + cc];
  #pragma unroll
  for (int mi = 0; mi < 4; ++mi) {
    #pragma unroll
    for (int i = 0; i < 4; ++i) {
      const int row = m0 + wm * 64 + mi * 16 + 4 * q + i;
      bf16x4 v = (bf16x4){(bf16_t)(acc[mi][0][i] + bv0), (bf16_t)(acc[mi][1][i] + bv1),
                          (bf16_t)(acc[mi][2][i] + bv2), (bf16_t)(acc[mi][3][i] + bv3)};
      *(bf16x4*)(xg2 + ((size_t)row * 256 + cc) * 4) = v;
    }
  }
}

// ---------------------------------------------------------------------------
// SLOW xg_gemm (fallback, proven round-3): fp32 inputs, VALU staging.
// ---------------------------------------------------------------------------
__global__ __launch_bounds__(512) void xg_gemm(
    const float* __restrict__ X, const float* __restrict__ Wih,
    const float* __restrict__ bias, bf16_t* __restrict__ xg2) {
  __shared__ __align__(16) bf16_t As[128][72];
  __shared__ __align__(16) bf16_t Bs[256][72];

  const int tid = threadIdx.x;
  const int lane = tid & 63;
  const int w = tid >> 6;
  const int q = lane >> 4;
  const int l15 = lane & 15;
  const int m0 = blockIdx.x * 128;
  const int ch0 = blockIdx.y * 64;

  f32x4 acc[16];
  #pragma unroll
  for (int n = 0; n < 16; ++n) acc[n] = (f32x4){0.f, 0.f, 0.f, 0.f};

  for (int kt = 0; kt < 8; ++kt) {
    const int k0 = kt * 64;
    __syncthreads();
    #pragma unroll
    for (int i = 0; i < 4; ++i) {
      int f = tid + 512 * i;
      int r = f >> 4, c4 = f & 15;
      float4 va = *(const float4*)(X + (size_t)(m0 + r) * D_ + k0 + c4 * 4);
      *(bf16x4*)&As[r][c4 * 4] =
          (bf16x4){(bf16_t)va.x, (bf16_t)va.y, (bf16_t)va.z, (bf16_t)va.w};
    }
    #pragma unroll
    for (int j = 0; j < 8; ++j) {
      int f = tid + 512 * j;
      int r = f >> 4, c4 = f & 15;
      int wr = (r >> 6) * 256 + ch0 + (r & 63);
      float4 vb = *(const float4*)(Wih + (size_t)wr * D_ + k0 + c4 * 4);
      *(bf16x4*)&Bs[r][c4 * 4] =
          (bf16x4){(bf16_t)vb.x, (bf16_t)vb.y, (bf16_t)vb.z, (bf16_t)vb.w};
    }
    __syncthreads();
    #pragma unroll
    for (int kk = 0; kk < 2; ++kk) {
      bf16x8 a = *(const bf16x8*)&As[16 * w + l15][kk * 32 + q * 8];
      #pragma unroll
      for (int n = 0; n < 16; ++n) {
        bf16x8 b = *(const bf16x8*)&Bs[16 * n + l15][kk * 32 + q * 8];
        acc[n] = __builtin_amdgcn_mfma_f32_16x16x32_bf16(a, b, acc[n], 0, 0, 0);
      }
    }
  }
  #pragma unroll
  for (int cs = 0; cs < 4; ++cs) {
    const int cc = ch0 + cs * 16 + l15;
    float bv0 = bias[cc], bv1 = bias[256 + cc];
    float bv2 = bias[512 + cc], bv3 = bias[768 + cc];
    #pragma unroll
    for (int i = 0; i < 4; ++i) {
      int row = m0 + 16 * w + 4 * q + i;
      bf16x4 v = (bf16x4){(bf16_t)(acc[cs][i] + bv0), (bf16_t)(acc[4 + cs][i] + bv1),
                          (bf16_t)(acc[8 + cs][i] + bv2), (bf16_t)(acc[12 + cs][i] + bv3)};
      *(bf16x4*)(xg2 + ((size_t)row * 256 + cc) * 4) = v;
    }
  }
}

// ---------------------------------------------------------------------------
// LSTM scan (unchanged, verified): 16 WGs x 8 batch rows, 8 waves/WG.
// ---------------------------------------------------------------------------
__global__ __launch_bounds__(512, 2) void lstm_scan(
    const bf16_t* __restrict__ xg2, const bf16_t* __restrict__ Whh,
    float* __restrict__ hT) {
  __shared__ __align__(16) bf16_t wlds[8 * 16 * 512];   // 128 KB
  __shared__ __align__(16) bf16_t hbuf[2][16][264];     // 16.9 KB

  const int tid = threadIdx.x;
  const int lane = tid & 63;
  const int w = tid >> 6;
  const int q = lane >> 4;
  const int l15 = lane & 15;
  const int b0 = blockIdx.x * 8;
  const int rq = (q & 1) * 4 + (q >> 1) * 2;
  const bool hi = (lane >= 32);

  bf16x8 wreg[6][8];
  #pragma unroll
  for (int p2 = 0; p2 < 2; ++p2) {
    #pragma unroll
    for (int g2 = 0; g2 < 4; ++g2) {
      const int j = p2 * 4 + g2;
      const bf16_t* src =
          Whh + (size_t)(g2 * 256 + 32 * w + 16 * p2 + l15) * H_ + q * 8;
      #pragma unroll
      for (int kk = 0; kk < 8; ++kk) {
        bf16x8 v = *(const bf16x8*)(src + kk * 32);
        if (j < 6) {
          wreg[j][kk] = v;
        } else {
          *(bf16x8*)&wlds[(size_t)((w * 16 + (g2 - 2) * 8 + kk)) * 512 + lane * 8] = v;
        }
      }
    }
  }

  for (int i = tid; i < 2 * 16 * 264; i += 512) ((bf16_t*)hbuf)[i] = (bf16_t)0.0f;
  __syncthreads();

  float cst[2][2];
  #pragma unroll
  for (int p = 0; p < 2; ++p) { cst[p][0] = 0.f; cst[p][1] = 0.f; }

  const bf16_t* xp[2][2];
  #pragma unroll
  for (int p = 0; p < 2; ++p)
    #pragma unroll
    for (int k = 0; k < 2; ++k)
      xp[p][k] = xg2 + (size_t)(b0 + rq + k) * (size_t)T_ * 1024 + (32 * w + 16 * p + l15) * 4;

  bf16x4 xv[2][2], xn[2][2];
  #pragma unroll
  for (int p = 0; p < 2; ++p)
    #pragma unroll
    for (int k = 0; k < 2; ++k) {
      xv[p][k] = *(const bf16x4*)xp[p][k];
      xp[p][k] += 1024;
    }

  auto step = [&](int t, bf16x4 (&xc)[2][2], bf16x4 (&xf)[2][2]) {
    #pragma unroll
    for (int p = 0; p < 2; ++p)
      #pragma unroll
      for (int k = 0; k < 2; ++k) {
        xf[p][k] = *(const bf16x4*)xp[p][k];
        xp[p][k] += 1024;
      }
    const int cur = t & 1;
    #pragma unroll
    for (int p = 0; p < 2; ++p) {
      f32x4 acc[4];
      #pragma unroll
      for (int g = 0; g < 4; ++g) acc[g] = (f32x4){0.f, 0.f, 0.f, 0.f};
      #pragma unroll
      for (int kk = 0; kk < 8; ++kk) {
        bf16x8 a = *(const bf16x8*)&hbuf[cur][l15][kk * 32 + q * 8];
        if (p == 0) {
          acc[0] = __builtin_amdgcn_mfma_f32_16x16x32_bf16(a, wreg[0][kk], acc[0], 0, 0, 0);
          acc[1] = __builtin_amdgcn_mfma_f32_16x16x32_bf16(a, wreg[1][kk], acc[1], 0, 0, 0);
          acc[2] = __builtin_amdgcn_mfma_f32_16x16x32_bf16(a, wreg[2][kk], acc[2], 0, 0, 0);
          acc[3] = __builtin_amdgcn_mfma_f32_16x16x32_bf16(a, wreg[3][kk], acc[3], 0, 0, 0);
        } else {
          acc[0] = __builtin_amdgcn_mfma_f32_16x16x32_bf16(a, wreg[4][kk], acc[0], 0, 0, 0);
          acc[1] = __builtin_amdgcn_mfma_f32_16x16x32_bf16(a, wreg[5][kk], acc[1], 0, 0, 0);
          bf16x8 bg = *(const bf16x8*)&wlds[(size_t)(w * 16 + kk) * 512 + lane * 8];
          bf16x8 bo = *(const bf16x8*)&wlds[(size_t)(w * 16 + 8 + kk) * 512 + lane * 8];
          acc[2] = __builtin_amdgcn_mfma_f32_16x16x32_bf16(a, bg, acc[2], 0, 0, 0);
          acc[3] = __builtin_amdgcn_mfma_f32_16x16x32_bf16(a, bo, acc[3], 0, 0, 0);
        }
      }
      float G0[4], G1[4];
      #pragma unroll
      for (int g = 0; g < 4; ++g) {
        float s2 = __shfl(acc[g][2], lane ^ 32, 64);
        float s3 = __shfl(acc[g][3], lane ^ 32, 64);
        G0[g] = hi ? s2 : acc[g][0];
        G1[g] = hi ? s3 : acc[g][1];
      }
      const int c = 32 * w + 16 * p + l15;
      #pragma unroll
      for (int k = 0; k < 2; ++k) {
        const float* Gv_ = k ? G1 : G0;
        float gi = Gv_[0] + (float)xc[p][k][0];
        float gf = Gv_[1] + (float)xc[p][k][1];
        float gg = Gv_[2] + (float)xc[p][k][2];
        float go = Gv_[3] + (float)xc[p][k][3];
        float I = sigmoid_f(gi);
        float F = sigmoid_f(gf);
        float Gg = tanh_f(gg);
        float Ov = sigmoid_f(go);
        float cv = F * cst[p][k] + I * Gg;
        cst[p][k] = cv;
        float hv = Ov * tanh_f(cv);
        hbuf[cur ^ 1][rq + k][c] = (bf16_t)hv;
        if (t == T_ - 1) hT[(size_t)(b0 + rq + k) * H_ + c] = hv;
      }
    }
    barrier_lds_only();
  };

  #pragma unroll 1
  for (int t = 0; t < T_; t += 2) {
    step(t, xv, xn);
    step(t + 1, xn, xv);
  }
}

// ---------------------------------------------------------------------------
// out = h_T @ W_out^T + b_out
// ---------------------------------------------------------------------------
__global__ __launch_bounds__(128) void head_gemm(
    const float* __restrict__ hT, const float* __restrict__ Wout,
    const float* __restrict__ bout, float* __restrict__ out) {
  __shared__ float hrow[H_];
  const int b = blockIdx.x;
  const int o = threadIdx.x;
  hrow[o] = hT[(size_t)b * H_ + o];
  hrow[o + 128] = hT[(size_t)b * H_ + 128 + o];
  __syncthreads();
  float s = bout[o];
  const float* wr = Wout + (size_t)o * H_;
  #pragma unroll 8
  for (int j = 0; j < H_; ++j) s += hrow[j] * wr[j];
  out[(size_t)b * 128 + o] = s;
}

// ---------------------------------------------------------------------------
extern "C" void kernel_launch(void* const* d_in, const int* in_sizes, int n_in,
                              void* d_out, int out_size, void* d_ws, size_t ws_size,
                              hipStream_t stream) {
  const float* X    = (const float*)d_in[0];
  const float* Wih  = (const float*)d_in[1];
  const float* Whh  = (const float*)d_in[2];
  const float* bih  = (const float*)d_in[3];
  const float* bhh  = (const float*)d_in[4];
  const float* Wout = (const float*)d_in[5];
  const float* bout = (const float*)d_in[6];
  float* out = (float*)d_out;

  // workspace layout (bytes). Prefix is byte-identical to the proven layout;
  // wihb/xb exist only on the fast path, gated on ws_size.
  char* ws = (char*)d_ws;
  const size_t XG_BYTES   = (size_t)B_ * T_ * G_ * 2;   // 268435456
  const size_t WHHB_BYTES = (size_t)G_ * H_ * 2;        // 524288
  const size_t BIAS_BYTES = (size_t)G_ * 4;             // 4096
  const size_t HT_BYTES   = (size_t)B_ * H_ * 4;        // 131072
  const size_t WIHB_BYTES = (size_t)G_ * D_ * 2;        // 1048576
  const size_t XB_BYTES   = (size_t)B_ * T_ * D_ * 2;   // 134217728
  bf16_t* xg2  = (bf16_t*)ws;
  bf16_t* whhb = (bf16_t*)(ws + XG_BYTES);
  float*  bias = (float*)(ws + XG_BYTES + WHHB_BYTES);
  float*  hT   = (float*)(ws + XG_BYTES + WHHB_BYTES + BIAS_BYTES);
  bf16_t* wihb = (bf16_t*)(ws + XG_BYTES + WHHB_BYTES + BIAS_BYTES + HT_BYTES);
  bf16_t* xb   = (bf16_t*)(ws + XG_BYTES + WHHB_BYTES + BIAS_BYTES + HT_BYTES + WIHB_BYTES);

  const size_t NEED_FAST =
      XG_BYTES + WHHB_BYTES + BIAS_BYTES + HT_BYTES + WIHB_BYTES + XB_BYTES;

  if (ws_size >= NEED_FAST) {
    prep_full_kernel<<<dim3(2048), 256, 0, stream>>>(Whh, bih, bhh, Wih, whhb, wihb, bias);
    xconv_kernel<<<dim3(4096), 256, 0, stream>>>(X, xb);
    xg_gemm_fast<<<dim3((B_ * T_) / 128, 4), 512, 0, stream>>>(xb, wihb, bias, xg2);
  } else {
    prep_kernel<<<dim3(1024), 256, 0, stream>>>(Whh, bih, bhh, whhb, bias);
    xg_gemm<<<dim3((B_ * T_) / 128, 4), 512, 0, stream>>>(X, Wih, bias, xg2);
  }
  lstm_scan<<<dim3(B_ / 8), 512, 0, stream>>>(xg2, whhb, hT);
  head_gemm<<<dim3(B_), 128, 0, stream>>>(hT, Wout, bout, out);
}